// Round 1
// baseline (7209.570 us; speedup 1.0000x reference)
//
#include <hip/hip_runtime.h>
#include <hip/hip_bf16.h>

#define TD 384
#define NHEAD 6
#define NFF 1536
#define NB 16
#define NTOK 481
#define NROWS (NB*NTOK)   // 7696

static __device__ __forceinline__ float gelu_f(float v){
    return 0.5f*v*(1.0f + erff(v*0.70710678118654752f));
}

// ---------------- generic fp32 GEMM: C = scale*(A @ B^T) + bias [+gelu] [+R] ----------------
// A: (M,K) row-major lda; B: (N,K) row-major ldb; C: (M,N) ldc. Batched via grid.z + strides.
__global__ __launch_bounds__(256) void gemm_kernel(
    const float* __restrict__ A, int lda, long sA,
    const float* __restrict__ Bm, int ldb, long sB,
    float* __restrict__ C, int ldc, long sC,
    const float* __restrict__ bias,
    const float* __restrict__ Rp, long sR,
    int M, int N, int K, float scale, int act)
{
    __shared__ float As[16][68];
    __shared__ float Bs[16][68];
    const int bz = blockIdx.z;
    A  += (long)bz*sA; Bm += (long)bz*sB; C += (long)bz*sC;
    const int m0 = blockIdx.y*64, n0 = blockIdx.x*64;
    const int tid = threadIdx.x;
    const int tx = tid & 15, ty = tid >> 4;
    const int lr = tid >> 2, lq = tid & 3;
    float acc[4][4] = {};
    const bool am = (m0 + lr < M), bn = (n0 + lr < N);
    const float* ap = A  + (long)(m0+lr)*lda + lq*4;
    const float* bp = Bm + (long)(n0+lr)*ldb + lq*4;
    for (int k0 = 0; k0 < K; k0 += 16) {
        float4 av = make_float4(0,0,0,0), bv = make_float4(0,0,0,0);
        if (am) av = *(const float4*)(ap + k0);
        if (bn) bv = *(const float4*)(bp + k0);
        __syncthreads();
        As[lq*4+0][lr]=av.x; As[lq*4+1][lr]=av.y; As[lq*4+2][lr]=av.z; As[lq*4+3][lr]=av.w;
        Bs[lq*4+0][lr]=bv.x; Bs[lq*4+1][lr]=bv.y; Bs[lq*4+2][lr]=bv.z; Bs[lq*4+3][lr]=bv.w;
        __syncthreads();
        #pragma unroll
        for (int k = 0; k < 16; ++k) {
            const float4 a4 = *(const float4*)&As[k][ty*4];
            const float4 b4 = *(const float4*)&Bs[k][tx*4];
            const float ar[4] = {a4.x,a4.y,a4.z,a4.w};
            const float br[4] = {b4.x,b4.y,b4.z,b4.w};
            #pragma unroll
            for (int e=0;e<4;++e)
                #pragma unroll
                for (int f=0;f<4;++f)
                    acc[e][f] += ar[e]*br[f];
        }
    }
    #pragma unroll
    for (int e=0;e<4;++e){
        int m = m0 + ty*4 + e;
        if (m >= M) continue;
        #pragma unroll
        for (int f=0;f<4;++f){
            int n = n0 + tx*4 + f;
            if (n >= N) continue;
            float v = acc[e][f]*scale;
            if (bias) v += bias[n];
            if (act == 1) v = gelu_f(v);
            if (Rp) v += Rp[(long)bz*sR + (long)m*ldc + n];
            C[(long)m*ldc + n] = v;
        }
    }
}

// ---------------- flash attention (fp32), one block per (q-tile, head, batch) ----------------
__global__ __launch_bounds__(256) void attn_kernel(const float* __restrict__ QKV, float* __restrict__ O)
{
    __shared__ float Qs[64][68];   // [d][m]
    __shared__ float KVs[64][68];  // K as [d][n], then V as [n][d]
    __shared__ float Ps[64][68];   // [n][m]
    const int qt = blockIdx.x, h = blockIdx.y, b = blockIdx.z;
    const int tid = threadIdx.x;
    const int tx = tid & 15, ty = tid >> 4;
    const float* base = QKV + (long)b * NTOK * 1152;

    for (int i = 0; i < 4; ++i) {
        int qi = tid + i*256;
        int row = qi >> 4, dq = qi & 15;
        int q = qt*64 + row;
        float4 v = make_float4(0,0,0,0);
        if (q < NTOK) v = *(const float4*)&base[(long)q*1152 + h*64 + dq*4];
        Qs[dq*4+0][row] = v.x*0.125f;
        Qs[dq*4+1][row] = v.y*0.125f;
        Qs[dq*4+2][row] = v.z*0.125f;
        Qs[dq*4+3][row] = v.w*0.125f;
    }

    float mo[4], lo[4], acc[4][4];
    #pragma unroll
    for (int e=0;e<4;++e){ mo[e]=-1e30f; lo[e]=0.f;
        #pragma unroll
        for (int f=0;f<4;++f) acc[e][f]=0.f; }

    for (int kt = 0; kt < 8; ++kt) {
        __syncthreads();
        for (int i = 0; i < 4; ++i) {          // stage K^T
            int ki = tid + i*256;
            int row = ki >> 4, dq = ki & 15;
            int k = kt*64 + row;
            float4 v = make_float4(0,0,0,0);
            if (k < NTOK) v = *(const float4*)&base[(long)k*1152 + 384 + h*64 + dq*4];
            KVs[dq*4+0][row] = v.x;
            KVs[dq*4+1][row] = v.y;
            KVs[dq*4+2][row] = v.z;
            KVs[dq*4+3][row] = v.w;
        }
        __syncthreads();
        float s[4][4] = {};
        for (int d = 0; d < 64; ++d) {
            const float4 a4 = *(const float4*)&Qs[d][ty*4];
            const float4 b4 = *(const float4*)&KVs[d][tx*4];
            const float ar[4] = {a4.x,a4.y,a4.z,a4.w};
            const float br[4] = {b4.x,b4.y,b4.z,b4.w};
            #pragma unroll
            for (int e=0;e<4;++e)
                #pragma unroll
                for (int f=0;f<4;++f)
                    s[e][f] += ar[e]*br[f];
        }
        #pragma unroll
        for (int f=0; f<4; ++f) {
            int n = kt*64 + tx*4 + f;
            if (n >= NTOK) { s[0][f]=-1e30f; s[1][f]=-1e30f; s[2][f]=-1e30f; s[3][f]=-1e30f; }
        }
        #pragma unroll
        for (int e=0;e<4;++e) {
            float rm = fmaxf(fmaxf(s[e][0],s[e][1]), fmaxf(s[e][2],s[e][3]));
            #pragma unroll
            for (int w=1; w<16; w<<=1) rm = fmaxf(rm, __shfl_xor(rm, w));
            float mn = fmaxf(mo[e], rm);
            float alpha = expf(mo[e]-mn);
            float rs = 0.f;
            #pragma unroll
            for (int f=0;f<4;++f){ float p = expf(s[e][f]-mn); s[e][f]=p; rs+=p; }
            #pragma unroll
            for (int w=1; w<16; w<<=1) rs += __shfl_xor(rs, w);
            lo[e] = lo[e]*alpha + rs;
            mo[e] = mn;
            #pragma unroll
            for (int f=0;f<4;++f) acc[e][f]*=alpha;
        }
        __syncthreads();   // everyone done reading K / previous Ps
        #pragma unroll
        for (int e=0;e<4;++e)
            #pragma unroll
            for (int f=0;f<4;++f)
                Ps[tx*4+f][ty*4+e] = s[e][f];
        for (int i = 0; i < 4; ++i) {          // stage V
            int ki = tid + i*256;
            int row = ki >> 4, dq = ki & 15;
            int k = kt*64 + row;
            float4 v = make_float4(0,0,0,0);
            if (k < NTOK) v = *(const float4*)&base[(long)k*1152 + 768 + h*64 + dq*4];
            KVs[row][dq*4+0]=v.x; KVs[row][dq*4+1]=v.y; KVs[row][dq*4+2]=v.z; KVs[row][dq*4+3]=v.w;
        }
        __syncthreads();
        for (int n = 0; n < 64; ++n) {
            const float4 p4 = *(const float4*)&Ps[n][ty*4];
            const float4 v4 = *(const float4*)&KVs[n][tx*4];
            const float pr[4] = {p4.x,p4.y,p4.z,p4.w};
            const float vr[4] = {v4.x,v4.y,v4.z,v4.w};
            #pragma unroll
            for (int e=0;e<4;++e)
                #pragma unroll
                for (int f=0;f<4;++f)
                    acc[e][f] += pr[e]*vr[f];
        }
    }
    #pragma unroll
    for (int e=0;e<4;++e){
        int q = qt*64 + ty*4 + e;
        if (q < NTOK){
            float inv = 1.f/lo[e];
            float* op = O + ((long)(b*NTOK+q))*TD + h*64 + tx*4;
            op[0]=acc[e][0]*inv; op[1]=acc[e][1]*inv; op[2]=acc[e][2]*inv; op[3]=acc[e][3]*inv;
        }
    }
}

// ---------------- LayerNorm: one block (128 threads) per row of 384 ----------------
__global__ __launch_bounds__(128) void ln_kernel(const float* __restrict__ Xp, float* __restrict__ Y,
    const float* __restrict__ W, const float* __restrict__ Bp)
{
    long r = blockIdx.x;
    int t = threadIdx.x;
    const float* x = Xp + r*TD;
    float v0 = x[t], v1 = x[t+128], v2 = x[t+256];
    float s = v0+v1+v2;
    float q = v0*v0+v1*v1+v2*v2;
    #pragma unroll
    for (int w=1; w<64; w<<=1){ s += __shfl_xor(s,w); q += __shfl_xor(q,w); }
    __shared__ float sm[2][2];
    if ((t&63)==0){ sm[t>>6][0]=s; sm[t>>6][1]=q; }
    __syncthreads();
    float S = sm[0][0]+sm[1][0];
    float Q = sm[0][1]+sm[1][1];
    float mean = S*(1.f/384.f);
    float var  = Q*(1.f/384.f) - mean*mean;
    float rstd = rsqrtf(var + 1e-6f);
    float* y = Y + r*TD;
    y[t]     = (v0-mean)*rstd*W[t]     + Bp[t];
    y[t+128] = (v1-mean)*rstd*W[t+128] + Bp[t+128];
    y[t+256] = (v2-mean)*rstd*W[t+256] + Bp[t+256];
}

// ---------------- im2col for the 16x16/stride-16 patch conv ----------------
__global__ void im2col_kernel(const float* __restrict__ in, float* __restrict__ outp)
{
    long idx = (long)blockIdx.x*256 + threadIdx.x;
    if (idx >= (long)7680*1792) return;
    int k = (int)(idx % 1792);
    long m = idx / 1792;
    int pw = (int)(m % 40);
    long t2 = m / 40;
    int ph = (int)(t2 % 12);
    int b  = (int)(t2 / 12);
    int kw = k & 15, kh = (k >> 4) & 15, c = k >> 8;
    outp[idx] = in[(((long)(b*7 + c)*192) + ph*16 + kh)*640 + pw*16 + kw];
}

// ---------------- assemble x = [cls; conv_out] + pos ----------------
__global__ void assemble_kernel(const float* __restrict__ CO, const float* __restrict__ cls,
    const float* __restrict__ pos, float* __restrict__ X)
{
    long idx = (long)blockIdx.x*256 + threadIdx.x;
    if (idx >= (long)NROWS*TD) return;
    int d = (int)(idx % TD);
    long r = idx / TD;
    int tok = (int)(r % NTOK);
    int b   = (int)(r / NTOK);
    float v = (tok == 0) ? cls[d] : CO[((long)b*480 + tok-1)*TD + d];
    X[idx] = v + pos[tok*TD + d];
}

// ---------------- pose maps: group-of-12 softmax + median mask, mean over queries ----------------
__global__ __launch_bounds__(256) void pose_maps_kernel(const float* __restrict__ PA,
    float* __restrict__ attn_map, float* __restrict__ masked_map)
{
    int i = blockIdx.x;   // 0..39
    int b = blockIdx.y;   // 0..15
    int t = threadIdx.x;
    float accA[12], accM[12];
    #pragma unroll
    for (int j=0;j<12;++j){ accA[j]=0.f; accM[j]=0.f; }
    for (int a = t; a < 480; a += 256) {
        const float* row = PA + ((long)(b*480 + a))*480 + i;
        float v[12];
        float mx = -1e30f;
        #pragma unroll
        for (int j=0;j<12;++j){ v[j] = row[40*j]; mx = fmaxf(mx, v[j]); }
        float sum = 0.f;
        #pragma unroll
        for (int j=0;j<12;++j){ v[j] = expf(v[j]-mx); sum += v[j]; }
        float invs = 1.f/sum;
        #pragma unroll
        for (int j=0;j<12;++j) v[j] *= invs;
        float srt[12];
        #pragma unroll
        for (int j=0;j<12;++j){
            float x = v[j]; int p = j;
            while (p > 0 && srt[p-1] > x){ srt[p]=srt[p-1]; --p; }
            srt[p]=x;
        }
        float med = srt[5];
        #pragma unroll
        for (int j=0;j<12;++j){
            accA[j] += v[j];
            accM[j] += (v[j] > med) ? 0.f : v[j];
        }
    }
    __shared__ float redA[256*12];
    __shared__ float redM[256*12];
    #pragma unroll
    for (int j=0;j<12;++j){ redA[t*12+j]=accA[j]; redM[t*12+j]=accM[j]; }
    __syncthreads();
    for (int sgap=128; sgap>0; sgap>>=1){
        if (t < sgap){
            #pragma unroll
            for (int j=0;j<12;++j){
                redA[t*12+j] += redA[(t+sgap)*12+j];
                redM[t*12+j] += redM[(t+sgap)*12+j];
            }
        }
        __syncthreads();
    }
    if (t < 12){
        attn_map  [(b*12 + t)*40 + i] = redA[t] * (1.f/480.f);
        masked_map[(b*12 + t)*40 + i] = redM[t] * (1.f/480.f) * (1.f/24.f);
    }
}

// ---------------- column-sum of pose V ----------------
__global__ __launch_bounds__(384) void colsum_kernel(const float* __restrict__ QKV2, float* __restrict__ CS)
{
    int b = blockIdx.x, c = threadIdx.x;
    const float* p = QKV2 + (long)b*480*1152 + 768 + c;
    float s = 0.f;
    for (int a = 0; a < 480; ++a) s += p[(long)a*1152];
    CS[b*384 + c] = s;
}

// ---------------- final pose output: LN(40*colsum @ pose_w^T + pose_b) ----------------
__global__ __launch_bounds__(384) void pose_final_kernel(const float* __restrict__ CS,
    const float* __restrict__ PW, const float* __restrict__ PB,
    const float* __restrict__ NW, const float* __restrict__ NBb, float* __restrict__ out)
{
    int b = blockIdx.x, c = threadIdx.x;
    const float* s0 = CS + b*384;
    const float* wr = PW + (long)c*384;
    float acc = 0.f;
    for (int k = 0; k < 384; ++k) acc += s0[k]*wr[k];
    acc = 40.f*acc + PB[c];
    float s = acc, q = acc*acc;
    #pragma unroll
    for (int w=1; w<64; w<<=1){ s += __shfl_xor(s,w); q += __shfl_xor(q,w); }
    __shared__ float sm[6][2];
    if ((c & 63) == 0){ sm[c>>6][0]=s; sm[c>>6][1]=q; }
    __syncthreads();
    float S=0.f, Q=0.f;
    for (int i=0;i<6;++i){ S+=sm[i][0]; Q+=sm[i][1]; }
    float mean = S*(1.f/384.f);
    float var  = Q*(1.f/384.f) - mean*mean;
    float rstd = rsqrtf(var + 1e-6f);
    out[b*384 + c] = (acc-mean)*rstd*NW[c] + NBb[c];
}

extern "C" void kernel_launch(void* const* d_in, const int* in_sizes, int n_in,
                              void* d_out, int out_size, void* d_ws, size_t ws_size,
                              hipStream_t stream)
{
    const float* input  = (const float*)d_in[0];
    const float* conv_w = (const float*)d_in[1];
    const float* conv_b = (const float*)d_in[2];
    const float* cls    = (const float*)d_in[3];
    const float* pos    = (const float*)d_in[4];
    const float* ln1w   = (const float*)d_in[5];
    const float* ln1b   = (const float*)d_in[6];
    const float* qkvw   = (const float*)d_in[7];
    const float* qkvb   = (const float*)d_in[8];
    const float* projw  = (const float*)d_in[9];
    const float* projb  = (const float*)d_in[10];
    const float* ln2w   = (const float*)d_in[11];
    const float* ln2b   = (const float*)d_in[12];
    const float* fc1w   = (const float*)d_in[13];
    const float* fc1b   = (const float*)d_in[14];
    const float* fc2w   = (const float*)d_in[15];
    const float* fc2b   = (const float*)d_in[16];
    const float* normw  = (const float*)d_in[17];
    const float* normb  = (const float*)d_in[18];
    const float* toqkvw = (const float*)d_in[19];
    const float* posew  = (const float*)d_in[20];
    const float* poseb  = (const float*)d_in[21];
    float* out = (float*)d_out;
    float* ws  = (float*)d_ws;

    float* X    = ws;                      // 7696*384  = 2,955,264
    float* H    = X   + 2955264;           // 7696*384
    float* QKV  = H   + 2955264;           // 7696*1536 = 11,821,056 (qkv / FF / pose-qkv)
    float* Obuf = QKV + 11821056;          // 7696*384
    float* PA   = Obuf + 2955264;          // 16*480*480 = 3,686,400
    float* CS   = PA  + 3686400;           // 16*384
    float* IM2C = QKV;                     // alias: 7680*1792 = 13,762,560 fits in QKV+Obuf

    // patch embed (im2col + GEMM) then token assembly
    {
        long total = (long)7680*1792;
        im2col_kernel<<<dim3((unsigned)((total+255)/256)), 256, 0, stream>>>(input, IM2C);
    }
    gemm_kernel<<<dim3(6, 120, 1), 256, 0, stream>>>(IM2C, 1792, 0, conv_w, 1792, 0,
        H, 384, 0, conv_b, nullptr, 0, 7680, 384, 1792, 1.f, 0);
    assemble_kernel<<<dim3((NROWS*TD+255)/256), 256, 0, stream>>>(H, cls, pos, X);

    for (int i = 0; i < 12; ++i) {
        ln_kernel<<<dim3(NROWS), 128, 0, stream>>>(X, H, ln1w + i*384, ln1b + i*384);
        gemm_kernel<<<dim3(18, 121, 1), 256, 0, stream>>>(H, 384, 0, qkvw + (long)i*1152*384, 384, 0,
            QKV, 1152, 0, qkvb + i*1152, nullptr, 0, NROWS, 1152, 384, 1.f, 0);
        attn_kernel<<<dim3(8, NHEAD, NB), 256, 0, stream>>>(QKV, Obuf);
        gemm_kernel<<<dim3(6, 121, 1), 256, 0, stream>>>(Obuf, 384, 0, projw + (long)i*384*384, 384, 0,
            X, 384, 0, projb + i*384, X, 0, NROWS, 384, 384, 1.f, 0);
        ln_kernel<<<dim3(NROWS), 128, 0, stream>>>(X, H, ln2w + i*384, ln2b + i*384);
        gemm_kernel<<<dim3(24, 121, 1), 256, 0, stream>>>(H, 384, 0, fc1w + (long)i*1536*384, 384, 0,
            QKV, 1536, 0, fc1b + i*1536, nullptr, 0, NROWS, 1536, 384, 1.f, 1);
        gemm_kernel<<<dim3(6, 121, 1), 256, 0, stream>>>(QKV, 1536, 0, fc2w + (long)i*384*1536, 1536, 0,
            X, 384, 0, fc2b + i*384, X, 0, NROWS, 384, 1536, 1.f, 0);
    }
    ln_kernel<<<dim3(NROWS), 128, 0, stream>>>(X, H, normw, normb);

    // pose head
    gemm_kernel<<<dim3(18, 8, 16), 256, 0, stream>>>(H + 384, 384, (long)481*384,
        toqkvw, 384, 0, QKV, 1152, (long)480*1152, nullptr, nullptr, 0, 480, 1152, 384, 1.f, 0);
    gemm_kernel<<<dim3(8, 8, 16), 256, 0, stream>>>(QKV, 1152, (long)480*1152,
        QKV + 384, 1152, (long)480*1152, PA, 480, (long)480*480, nullptr, nullptr, 0,
        480, 480, 384, 0.05103f*0.01f, 0);
    pose_maps_kernel<<<dim3(40, 16), 256, 0, stream>>>(PA, out + 6144, out + 13824);
    colsum_kernel<<<dim3(16), 384, 0, stream>>>(QKV, CS);
    pose_final_kernel<<<dim3(16), 384, 0, stream>>>(CS, posew, poseb, normw, normb, out);
}

// Round 2
// 5085.200 us; speedup vs baseline: 1.4178x; 1.4178x over previous
//
#include <hip/hip_runtime.h>
#include <hip/hip_bf16.h>

#define TD 384
#define NHEAD 6
#define NFF 1536
#define NB 16
#define NTOK 481
#define NROWS (NB*NTOK)   // 7696

typedef __attribute__((ext_vector_type(8))) __bf16 bf16x8;
typedef __attribute__((ext_vector_type(4))) __bf16 bf16x4;
typedef __attribute__((ext_vector_type(4))) float f32x4;

static __device__ __forceinline__ float gelu_f(float v){
    return 0.5f*v*(1.0f + erff(v*0.70710678118654752f));
}

// ---------------- bf16 MFMA GEMM: C = scale*(A @ B^T) + bias [+gelu] [+R] ----------------
// A: (M,K) fp32 row-major lda; B: (N,K) fp32 row-major ldb; C: (M,N) fp32 ldc.
// K must be a multiple of 64. Block = 256 threads = 4 waves in a 2x2 grid.
#define LDT 72   // padded LDS row (bf16 elems) for BK=64
template<int BM, int BN>
__global__ __launch_bounds__(256) void mgemm(
    const float* __restrict__ A, int lda, long sA,
    const float* __restrict__ Bm, int ldb, long sB,
    float* __restrict__ C, int ldc, long sC,
    const float* __restrict__ bias,
    const float* __restrict__ Rp, long sR,
    int M, int N, int K, float scale, int act)
{
    constexpr int FM = BM/32, FN = BN/32;  // fragments per wave (wave grid 2x2)
    __shared__ __bf16 As[BM*LDT];
    __shared__ __bf16 Bs[BN*LDT];
    const int bz = blockIdx.z;
    A  += (long)bz*sA; Bm += (long)bz*sB; C += (long)bz*sC;
    const int m0 = blockIdx.y*BM, n0 = blockIdx.x*BN;
    const int tid = threadIdx.x;
    const int w = tid >> 6, lane = tid & 63;
    const int wr = w >> 1, wc = w & 1;
    const int lr = lane & 15, lg = lane >> 4;
    const int arow = tid >> 4;        // 0..15 (+16 per iter)
    const int kc4  = (tid & 15) * 4;  // fp32 col offset within 64-wide K-slab

    f32x4 acc[FM][FN];
    #pragma unroll
    for (int m=0;m<FM;++m)
        #pragma unroll
        for (int n=0;n<FN;++n)
            acc[m][n] = (f32x4){0.f,0.f,0.f,0.f};

    for (int k0 = 0; k0 < K; k0 += 64) {
        __syncthreads();   // previous iteration done reading LDS
        #pragma unroll
        for (int it = 0; it < BM/16; ++it) {
            int r = arow + it*16;
            int gm = m0 + r;
            float4 v = make_float4(0,0,0,0);
            if (gm < M) v = *(const float4*)(A + (long)gm*lda + k0 + kc4);
            bf16x4 p; p[0]=(__bf16)v.x; p[1]=(__bf16)v.y; p[2]=(__bf16)v.z; p[3]=(__bf16)v.w;
            *(bf16x4*)&As[r*LDT + kc4] = p;
        }
        #pragma unroll
        for (int it = 0; it < BN/16; ++it) {
            int r = arow + it*16;
            int gn = n0 + r;
            float4 v = make_float4(0,0,0,0);
            if (gn < N) v = *(const float4*)(Bm + (long)gn*ldb + k0 + kc4);
            bf16x4 p; p[0]=(__bf16)v.x; p[1]=(__bf16)v.y; p[2]=(__bf16)v.z; p[3]=(__bf16)v.w;
            *(bf16x4*)&Bs[r*LDT + kc4] = p;
        }
        __syncthreads();
        #pragma unroll
        for (int kk = 0; kk < 2; ++kk) {
            bf16x8 af[FM], bfr[FN];
            #pragma unroll
            for (int m=0;m<FM;++m)
                af[m] = *(const bf16x8*)&As[(wr*(BM/2) + m*16 + lr)*LDT + kk*32 + lg*8];
            #pragma unroll
            for (int n=0;n<FN;++n)
                bfr[n] = *(const bf16x8*)&Bs[(wc*(BN/2) + n*16 + lr)*LDT + kk*32 + lg*8];
            #pragma unroll
            for (int m=0;m<FM;++m)
                #pragma unroll
                for (int n=0;n<FN;++n)
                    acc[m][n] = __builtin_amdgcn_mfma_f32_16x16x32_bf16(af[m], bfr[n], acc[m][n], 0, 0, 0);
        }
    }

    #pragma unroll
    for (int m=0;m<FM;++m){
        int rowb = m0 + wr*(BM/2) + m*16 + lg*4;
        #pragma unroll
        for (int n=0;n<FN;++n){
            int col = n0 + wc*(BN/2) + n*16 + lr;
            if (col >= N) continue;
            #pragma unroll
            for (int e=0;e<4;++e){
                int row = rowb + e;
                if (row >= M) continue;
                float v = acc[m][n][e]*scale;
                if (bias) v += bias[col];
                if (act == 1) v = gelu_f(v);
                if (Rp) v += Rp[(long)bz*sR + (long)row*ldc + col];
                C[(long)row*ldc + col] = v;
            }
        }
    }
}

// ---------------- flash attention (fp32), one block per (q-tile, head, batch) ----------------
__global__ __launch_bounds__(256) void attn_kernel(const float* __restrict__ QKV, float* __restrict__ O)
{
    __shared__ float Qs[64][68];   // [d][m]
    __shared__ float KVs[64][68];  // K as [d][n], then V as [n][d]
    __shared__ float Ps[64][68];   // [n][m]
    const int qt = blockIdx.x, h = blockIdx.y, b = blockIdx.z;
    const int tid = threadIdx.x;
    const int tx = tid & 15, ty = tid >> 4;
    const float* base = QKV + (long)b * NTOK * 1152;

    for (int i = 0; i < 4; ++i) {
        int qi = tid + i*256;
        int row = qi >> 4, dq = qi & 15;
        int q = qt*64 + row;
        float4 v = make_float4(0,0,0,0);
        if (q < NTOK) v = *(const float4*)&base[(long)q*1152 + h*64 + dq*4];
        Qs[dq*4+0][row] = v.x*0.125f;
        Qs[dq*4+1][row] = v.y*0.125f;
        Qs[dq*4+2][row] = v.z*0.125f;
        Qs[dq*4+3][row] = v.w*0.125f;
    }

    float mo[4], lo[4], acc[4][4];
    #pragma unroll
    for (int e=0;e<4;++e){ mo[e]=-1e30f; lo[e]=0.f;
        #pragma unroll
        for (int f=0;f<4;++f) acc[e][f]=0.f; }

    for (int kt = 0; kt < 8; ++kt) {
        __syncthreads();
        for (int i = 0; i < 4; ++i) {          // stage K^T
            int ki = tid + i*256;
            int row = ki >> 4, dq = ki & 15;
            int k = kt*64 + row;
            float4 v = make_float4(0,0,0,0);
            if (k < NTOK) v = *(const float4*)&base[(long)k*1152 + 384 + h*64 + dq*4];
            KVs[dq*4+0][row] = v.x;
            KVs[dq*4+1][row] = v.y;
            KVs[dq*4+2][row] = v.z;
            KVs[dq*4+3][row] = v.w;
        }
        __syncthreads();
        float s[4][4] = {};
        for (int d = 0; d < 64; ++d) {
            const float4 a4 = *(const float4*)&Qs[d][ty*4];
            const float4 b4 = *(const float4*)&KVs[d][tx*4];
            const float ar[4] = {a4.x,a4.y,a4.z,a4.w};
            const float br[4] = {b4.x,b4.y,b4.z,b4.w};
            #pragma unroll
            for (int e=0;e<4;++e)
                #pragma unroll
                for (int f=0;f<4;++f)
                    s[e][f] += ar[e]*br[f];
        }
        #pragma unroll
        for (int f=0; f<4; ++f) {
            int n = kt*64 + tx*4 + f;
            if (n >= NTOK) { s[0][f]=-1e30f; s[1][f]=-1e30f; s[2][f]=-1e30f; s[3][f]=-1e30f; }
        }
        #pragma unroll
        for (int e=0;e<4;++e) {
            float rm = fmaxf(fmaxf(s[e][0],s[e][1]), fmaxf(s[e][2],s[e][3]));
            #pragma unroll
            for (int w=1; w<16; w<<=1) rm = fmaxf(rm, __shfl_xor(rm, w));
            float mn = fmaxf(mo[e], rm);
            float alpha = expf(mo[e]-mn);
            float rs = 0.f;
            #pragma unroll
            for (int f=0;f<4;++f){ float p = expf(s[e][f]-mn); s[e][f]=p; rs+=p; }
            #pragma unroll
            for (int w=1; w<16; w<<=1) rs += __shfl_xor(rs, w);
            lo[e] = lo[e]*alpha + rs;
            mo[e] = mn;
            #pragma unroll
            for (int f=0;f<4;++f) acc[e][f]*=alpha;
        }
        __syncthreads();   // everyone done reading K / previous Ps
        #pragma unroll
        for (int e=0;e<4;++e)
            #pragma unroll
            for (int f=0;f<4;++f)
                Ps[tx*4+f][ty*4+e] = s[e][f];
        for (int i = 0; i < 4; ++i) {          // stage V
            int ki = tid + i*256;
            int row = ki >> 4, dq = ki & 15;
            int k = kt*64 + row;
            float4 v = make_float4(0,0,0,0);
            if (k < NTOK) v = *(const float4*)&base[(long)k*1152 + 768 + h*64 + dq*4];
            KVs[row][dq*4+0]=v.x; KVs[row][dq*4+1]=v.y; KVs[row][dq*4+2]=v.z; KVs[row][dq*4+3]=v.w;
        }
        __syncthreads();
        for (int n = 0; n < 64; ++n) {
            const float4 p4 = *(const float4*)&Ps[n][ty*4];
            const float4 v4 = *(const float4*)&KVs[n][tx*4];
            const float pr[4] = {p4.x,p4.y,p4.z,p4.w};
            const float vr[4] = {v4.x,v4.y,v4.z,v4.w};
            #pragma unroll
            for (int e=0;e<4;++e)
                #pragma unroll
                for (int f=0;f<4;++f)
                    acc[e][f] += pr[e]*vr[f];
        }
    }
    #pragma unroll
    for (int e=0;e<4;++e){
        int q = qt*64 + ty*4 + e;
        if (q < NTOK){
            float inv = 1.f/lo[e];
            float* op = O + ((long)(b*NTOK+q))*TD + h*64 + tx*4;
            op[0]=acc[e][0]*inv; op[1]=acc[e][1]*inv; op[2]=acc[e][2]*inv; op[3]=acc[e][3]*inv;
        }
    }
}

// ---------------- LayerNorm: one block (128 threads) per row of 384 ----------------
__global__ __launch_bounds__(128) void ln_kernel(const float* __restrict__ Xp, float* __restrict__ Y,
    const float* __restrict__ W, const float* __restrict__ Bp)
{
    long r = blockIdx.x;
    int t = threadIdx.x;
    const float* x = Xp + r*TD;
    float v0 = x[t], v1 = x[t+128], v2 = x[t+256];
    float s = v0+v1+v2;
    float q = v0*v0+v1*v1+v2*v2;
    #pragma unroll
    for (int w=1; w<64; w<<=1){ s += __shfl_xor(s,w); q += __shfl_xor(q,w); }
    __shared__ float sm[2][2];
    if ((t&63)==0){ sm[t>>6][0]=s; sm[t>>6][1]=q; }
    __syncthreads();
    float S = sm[0][0]+sm[1][0];
    float Q = sm[0][1]+sm[1][1];
    float mean = S*(1.f/384.f);
    float var  = Q*(1.f/384.f) - mean*mean;
    float rstd = rsqrtf(var + 1e-6f);
    float* y = Y + r*TD;
    y[t]     = (v0-mean)*rstd*W[t]     + Bp[t];
    y[t+128] = (v1-mean)*rstd*W[t+128] + Bp[t+128];
    y[t+256] = (v2-mean)*rstd*W[t+256] + Bp[t+256];
}

// ---------------- im2col for the 16x16/stride-16 patch conv ----------------
__global__ void im2col_kernel(const float* __restrict__ in, float* __restrict__ outp)
{
    long idx = (long)blockIdx.x*256 + threadIdx.x;
    if (idx >= (long)7680*1792) return;
    int k = (int)(idx % 1792);
    long m = idx / 1792;
    int pw = (int)(m % 40);
    long t2 = m / 40;
    int ph = (int)(t2 % 12);
    int b  = (int)(t2 / 12);
    int kw = k & 15, kh = (k >> 4) & 15, c = k >> 8;
    outp[idx] = in[(((long)(b*7 + c)*192) + ph*16 + kh)*640 + pw*16 + kw];
}

// ---------------- assemble x = [cls; conv_out] + pos ----------------
__global__ void assemble_kernel(const float* __restrict__ CO, const float* __restrict__ cls,
    const float* __restrict__ pos, float* __restrict__ X)
{
    long idx = (long)blockIdx.x*256 + threadIdx.x;
    if (idx >= (long)NROWS*TD) return;
    int d = (int)(idx % TD);
    long r = idx / TD;
    int tok = (int)(r % NTOK);
    int b   = (int)(r / NTOK);
    float v = (tok == 0) ? cls[d] : CO[((long)b*480 + tok-1)*TD + d];
    X[idx] = v + pos[tok*TD + d];
}

// ---------------- pose maps: group-of-12 softmax + median mask, mean over queries ----------------
__global__ __launch_bounds__(256) void pose_maps_kernel(const float* __restrict__ PA,
    float* __restrict__ attn_map, float* __restrict__ masked_map)
{
    int i = blockIdx.x;   // 0..39
    int b = blockIdx.y;   // 0..15
    int t = threadIdx.x;
    float accA[12], accM[12];
    #pragma unroll
    for (int j=0;j<12;++j){ accA[j]=0.f; accM[j]=0.f; }
    for (int a = t; a < 480; a += 256) {
        const float* row = PA + ((long)(b*480 + a))*480 + i;
        float v[12];
        float mx = -1e30f;
        #pragma unroll
        for (int j=0;j<12;++j){ v[j] = row[40*j]; mx = fmaxf(mx, v[j]); }
        float sum = 0.f;
        #pragma unroll
        for (int j=0;j<12;++j){ v[j] = expf(v[j]-mx); sum += v[j]; }
        float invs = 1.f/sum;
        #pragma unroll
        for (int j=0;j<12;++j) v[j] *= invs;
        float srt[12];
        #pragma unroll
        for (int j=0;j<12;++j){
            float x = v[j]; int p = j;
            while (p > 0 && srt[p-1] > x){ srt[p]=srt[p-1]; --p; }
            srt[p]=x;
        }
        float med = srt[5];
        #pragma unroll
        for (int j=0;j<12;++j){
            accA[j] += v[j];
            accM[j] += (v[j] > med) ? 0.f : v[j];
        }
    }
    __shared__ float redA[256*12];
    __shared__ float redM[256*12];
    #pragma unroll
    for (int j=0;j<12;++j){ redA[t*12+j]=accA[j]; redM[t*12+j]=accM[j]; }
    __syncthreads();
    for (int sgap=128; sgap>0; sgap>>=1){
        if (t < sgap){
            #pragma unroll
            for (int j=0;j<12;++j){
                redA[t*12+j] += redA[(t+sgap)*12+j];
                redM[t*12+j] += redM[(t+sgap)*12+j];
            }
        }
        __syncthreads();
    }
    if (t < 12){
        attn_map  [(b*12 + t)*40 + i] = redA[t] * (1.f/480.f);
        masked_map[(b*12 + t)*40 + i] = redM[t] * (1.f/480.f) * (1.f/24.f);
    }
}

// ---------------- column-sum of pose V ----------------
__global__ __launch_bounds__(384) void colsum_kernel(const float* __restrict__ QKV2, float* __restrict__ CS)
{
    int b = blockIdx.x, c = threadIdx.x;
    const float* p = QKV2 + (long)b*480*1152 + 768 + c;
    float s = 0.f;
    for (int a = 0; a < 480; ++a) s += p[(long)a*1152];
    CS[b*384 + c] = s;
}

// ---------------- final pose output: LN(40*colsum @ pose_w^T + pose_b) ----------------
__global__ __launch_bounds__(384) void pose_final_kernel(const float* __restrict__ CS,
    const float* __restrict__ PW, const float* __restrict__ PB,
    const float* __restrict__ NW, const float* __restrict__ NBb, float* __restrict__ out)
{
    int b = blockIdx.x, c = threadIdx.x;
    const float* s0 = CS + b*384;
    const float* wr = PW + (long)c*384;
    float acc = 0.f;
    for (int k = 0; k < 384; ++k) acc += s0[k]*wr[k];
    acc = 40.f*acc + PB[c];
    float s = acc, q = acc*acc;
    #pragma unroll
    for (int w=1; w<64; w<<=1){ s += __shfl_xor(s,w); q += __shfl_xor(q,w); }
    __shared__ float sm[6][2];
    if ((c & 63) == 0){ sm[c>>6][0]=s; sm[c>>6][1]=q; }
    __syncthreads();
    float S=0.f, Q=0.f;
    for (int i=0;i<6;++i){ S+=sm[i][0]; Q+=sm[i][1]; }
    float mean = S*(1.f/384.f);
    float var  = Q*(1.f/384.f) - mean*mean;
    float rstd = rsqrtf(var + 1e-6f);
    out[b*384 + c] = (acc-mean)*rstd*NW[c] + NBb[c];
}

extern "C" void kernel_launch(void* const* d_in, const int* in_sizes, int n_in,
                              void* d_out, int out_size, void* d_ws, size_t ws_size,
                              hipStream_t stream)
{
    const float* input  = (const float*)d_in[0];
    const float* conv_w = (const float*)d_in[1];
    const float* conv_b = (const float*)d_in[2];
    const float* cls    = (const float*)d_in[3];
    const float* pos    = (const float*)d_in[4];
    const float* ln1w   = (const float*)d_in[5];
    const float* ln1b   = (const float*)d_in[6];
    const float* qkvw   = (const float*)d_in[7];
    const float* qkvb   = (const float*)d_in[8];
    const float* projw  = (const float*)d_in[9];
    const float* projb  = (const float*)d_in[10];
    const float* ln2w   = (const float*)d_in[11];
    const float* ln2b   = (const float*)d_in[12];
    const float* fc1w   = (const float*)d_in[13];
    const float* fc1b   = (const float*)d_in[14];
    const float* fc2w   = (const float*)d_in[15];
    const float* fc2b   = (const float*)d_in[16];
    const float* normw  = (const float*)d_in[17];
    const float* normb  = (const float*)d_in[18];
    const float* toqkvw = (const float*)d_in[19];
    const float* posew  = (const float*)d_in[20];
    const float* poseb  = (const float*)d_in[21];
    float* out = (float*)d_out;
    float* ws  = (float*)d_ws;

    float* X    = ws;                      // 7696*384  = 2,955,264
    float* H    = X   + 2955264;           // 7696*384
    float* QKV  = H   + 2955264;           // 7696*1536 = 11,821,056 (qkv / FF / pose-qkv)
    float* Obuf = QKV + 11821056;          // 7696*384
    float* PA   = Obuf + 2955264;          // 16*480*480 = 3,686,400
    float* CS   = PA  + 3686400;           // 16*384
    float* IM2C = QKV;                     // alias: 7680*1792 fits in QKV+Obuf

    // patch embed (im2col + GEMM) then token assembly
    {
        long total = (long)7680*1792;
        im2col_kernel<<<dim3((unsigned)((total+255)/256)), 256, 0, stream>>>(input, IM2C);
    }
    mgemm<64,128><<<dim3(3, 120, 1), 256, 0, stream>>>(IM2C, 1792, 0, conv_w, 1792, 0,
        H, 384, 0, conv_b, nullptr, 0, 7680, 384, 1792, 1.f, 0);
    assemble_kernel<<<dim3((NROWS*TD+255)/256), 256, 0, stream>>>(H, cls, pos, X);

    for (int i = 0; i < 12; ++i) {
        ln_kernel<<<dim3(NROWS), 128, 0, stream>>>(X, H, ln1w + i*384, ln1b + i*384);
        mgemm<128,128><<<dim3(9, 61, 1), 256, 0, stream>>>(H, 384, 0, qkvw + (long)i*1152*384, 384, 0,
            QKV, 1152, 0, qkvb + i*1152, nullptr, 0, NROWS, 1152, 384, 1.f, 0);
        attn_kernel<<<dim3(8, NHEAD, NB), 256, 0, stream>>>(QKV, Obuf);
        mgemm<64,128><<<dim3(3, 121, 1), 256, 0, stream>>>(Obuf, 384, 0, projw + (long)i*384*384, 384, 0,
            X, 384, 0, projb + i*384, X, 0, NROWS, 384, 384, 1.f, 0);
        ln_kernel<<<dim3(NROWS), 128, 0, stream>>>(X, H, ln2w + i*384, ln2b + i*384);
        mgemm<128,128><<<dim3(12, 61, 1), 256, 0, stream>>>(H, 384, 0, fc1w + (long)i*1536*384, 384, 0,
            QKV, 1536, 0, fc1b + i*1536, nullptr, 0, NROWS, 1536, 384, 1.f, 1);
        mgemm<64,128><<<dim3(3, 121, 1), 256, 0, stream>>>(QKV, 1536, 0, fc2w + (long)i*384*1536, 1536, 0,
            X, 384, 0, fc2b + i*384, X, 0, NROWS, 384, 1536, 1.f, 0);
    }
    ln_kernel<<<dim3(NROWS), 128, 0, stream>>>(X, H, normw, normb);

    // pose head
    mgemm<128,128><<<dim3(9, 4, 16), 256, 0, stream>>>(H + 384, 384, (long)481*384,
        toqkvw, 384, 0, QKV, 1152, (long)480*1152, nullptr, nullptr, 0, 480, 1152, 384, 1.f, 0);
    mgemm<128,128><<<dim3(4, 4, 16), 256, 0, stream>>>(QKV, 1152, (long)480*1152,
        QKV + 384, 1152, (long)480*1152, PA, 480, (long)480*480, nullptr, nullptr, 0,
        480, 480, 384, 0.05103f*0.01f, 0);
    pose_maps_kernel<<<dim3(40, 16), 256, 0, stream>>>(PA, out + 6144, out + 13824);
    colsum_kernel<<<dim3(16), 384, 0, stream>>>(QKV, CS);
    pose_final_kernel<<<dim3(16), 384, 0, stream>>>(CS, posew, poseb, normw, normb, out);
}

// Round 3
// 2227.266 us; speedup vs baseline: 3.2370x; 2.2832x over previous
//
#include <hip/hip_runtime.h>
#include <hip/hip_bf16.h>

#define TD 384
#define NHEAD 6
#define NFF 1536
#define NB 16
#define NTOK 481
#define NROWS (NB*NTOK)   // 7696
#define MPAD 7744         // 121*64

typedef __attribute__((ext_vector_type(8))) __bf16 bf16x8;
typedef __attribute__((ext_vector_type(4))) __bf16 bf16x4;
typedef __attribute__((ext_vector_type(4))) float f32x4;

static __device__ __forceinline__ float gelu_f(float v){
    return 0.5f*v*(1.0f + erff(v*0.70710678118654752f));
}

static __device__ __forceinline__ void gload16(const void* g, void* l){
    __builtin_amdgcn_global_load_lds((const __attribute__((address_space(1))) void*)g,
                                     (__attribute__((address_space(3))) void*)l, 16, 0, 0);
}

// stage ROWS x 64 bf16 tile (row-major, 128B rows) into linear LDS via global_load_lds,
// with XOR-swizzled SOURCE address so that a swizzled ds_read returns linear data (T2, rule 21).
template<int ROWS>
static __device__ __forceinline__ void stageT(const __bf16* g, int ldel, __bf16* lds, int w, int lane){
    #pragma unroll
    for (int j = 0; j < ROWS/32; ++j){
        int i = w*(ROWS/32) + j;
        int ol = i*1024 + lane*16;
        int row = ol >> 7, colb = ol & 127;
        int sc = colb ^ ((row & 7) << 4);
        gload16((const char*)g + (long)row*ldel*2 + sc, (char*)lds + i*1024);
    }
}

// ---------------- bf16 MFMA GEMM: C = scale*(A @ B^T) + bias [+gelu] [+R fp32] ----------------
// A: (M,K) bf16 row-major lda (rows padded: OOB-row reads must stay in-allocation);
// B: (N,K) bf16 ldb; C fp32 or bf16 (obf). K % 64 == 0. 256 thr = 4 waves (2x2), tile 64x128.
__global__ __launch_bounds__(256) void mgemm(
    const __bf16* __restrict__ A, int lda, long sA,
    const __bf16* __restrict__ Bm, int ldb, long sB,
    void* __restrict__ Cp, int ldc, long sC,
    const float* __restrict__ bias,
    const float* __restrict__ Rp, long sR,
    int M, int N, int K, float scale, int act, int obf)
{
    __shared__ __align__(16) __bf16 As[2][64*64];
    __shared__ __align__(16) __bf16 Bs[2][128*64];
    const int bz = blockIdx.z;
    A  += (long)bz*sA; Bm += (long)bz*sB;
    const int m0 = blockIdx.y*64, n0 = blockIdx.x*128;
    const int tid = threadIdx.x;
    const int w = tid >> 6, lane = tid & 63;
    const int wr = w >> 1, wc = w & 1;
    const int lr = lane & 15, lg = lane >> 4;

    f32x4 acc[2][4];
    #pragma unroll
    for (int m=0;m<2;++m)
        #pragma unroll
        for (int n=0;n<4;++n)
            acc[m][n] = (f32x4){0.f,0.f,0.f,0.f};

    const __bf16* Ag = A + (long)m0*lda;
    const __bf16* Bg = Bm + (long)n0*ldb;
    const int NT = K >> 6;

    stageT<64>(Ag, lda, As[0], w, lane);
    stageT<128>(Bg, ldb, Bs[0], w, lane);
    __syncthreads();
    int cur = 0;
    for (int t = 0; t < NT; ++t){
        if (t+1 < NT){
            stageT<64>(Ag + (t+1)*64, lda, As[cur^1], w, lane);
            stageT<128>(Bg + (t+1)*64, ldb, Bs[cur^1], w, lane);
        }
        #pragma unroll
        for (int kk=0;kk<2;++kk){
            const int sa = ((kk*64 + lg*16) ^ ((lr&7)<<4));
            bf16x8 af[2], bfr[4];
            #pragma unroll
            for (int m=0;m<2;++m)
                af[m] = *(const bf16x8*)((const char*)&As[cur][0] + (wr*32 + m*16 + lr)*128 + sa);
            #pragma unroll
            for (int n=0;n<4;++n)
                bfr[n] = *(const bf16x8*)((const char*)&Bs[cur][0] + (wc*64 + n*16 + lr)*128 + sa);
            #pragma unroll
            for (int m=0;m<2;++m)
                #pragma unroll
                for (int n=0;n<4;++n)
                    acc[m][n] = __builtin_amdgcn_mfma_f32_16x16x32_bf16(af[m], bfr[n], acc[m][n], 0, 0, 0);
        }
        __syncthreads();   // drains vmcnt (stage t+1 done) + lgkm; then buffers swap
        cur ^= 1;
    }

    #pragma unroll
    for (int m=0;m<2;++m){
        #pragma unroll
        for (int n=0;n<4;++n){
            int col = n0 + wc*64 + n*16 + lr;
            if (col >= N) continue;
            #pragma unroll
            for (int e=0;e<4;++e){
                int row = m0 + wr*32 + m*16 + lg*4 + e;
                if (row >= M) continue;
                float v = acc[m][n][e]*scale;
                if (bias) v += bias[col];
                if (act) v = gelu_f(v);
                if (Rp) v += Rp[(long)bz*sR + (long)row*ldc + col];
                if (obf) ((__bf16*)Cp)[(long)bz*sC + (long)row*ldc + col] = (__bf16)v;
                else     ((float*)Cp)[(long)bz*sC + (long)row*ldc + col] = v;
            }
        }
    }
}

// ---------------- MFMA flash attention: block = (q-tile 64, head, batch), 4 waves ----------------
// Wave w owns q-rows [qt*64+w*16, +16). Q in regs; K swizzled-LDS; V,P padded LDS.
__global__ __launch_bounds__(256) void attn2(const __bf16* __restrict__ QKV, __bf16* __restrict__ O)
{
    __shared__ __align__(16) __bf16 Ks[64*64];
    __shared__ __align__(16) __bf16 VT[64*72];
    __shared__ __align__(16) __bf16 Ps[64*72];
    const int qt=blockIdx.x, h=blockIdx.y, b=blockIdx.z;
    const int tid=threadIdx.x, w=tid>>6, lane=tid&63;
    const int lr=lane&15, lg=lane>>4;
    const __bf16* base = QKV + (long)b*NTOK*1152;
    const long qrow = qt*64 + w*16 + lr;
    const bf16x8 qa0 = *(const bf16x8*)(base + qrow*1152 + h*64 + lg*8);
    const bf16x8 qa1 = *(const bf16x8*)(base + qrow*1152 + h*64 + 32 + lg*8);

    f32x4 oacc[4];
    float mo[4], lo[4];
    #pragma unroll
    for (int e=0;e<4;++e){ mo[e]=-1e30f; lo[e]=0.f; }
    #pragma unroll
    for (int n=0;n<4;++n) oacc[n]=(f32x4){0.f,0.f,0.f,0.f};

    for (int kt=0; kt<8; ++kt){
        __syncthreads();   // previous iteration's LDS readers done
        #pragma unroll
        for (int j=0;j<2;++j){
            int i = w*2+j;
            int ol = i*1024 + lane*16;
            int row = ol>>7, colb = ol&127;
            int sc = colb ^ ((row&7)<<4);
            gload16((const char*)base + ((long)(kt*64+row)*1152 + 384 + h*64)*2 + sc,
                    (char*)Ks + i*1024);
        }
        #pragma unroll
        for (int rep=0;rep<2;++rep){
            int c = tid + rep*256;
            int kv = c & 63, d8 = c >> 6;
            bf16x8 vv = *(const bf16x8*)(base + (long)(kt*64+kv)*1152 + 768 + h*64 + d8*8);
            #pragma unroll
            for (int jj=0;jj<8;++jj) VT[(d8*8+jj)*72 + kv] = vv[jj];
        }
        __syncthreads();   // staging visible (vmcnt+lgkm drained by barrier)

        f32x4 s[4];
        #pragma unroll
        for (int n=0;n<4;++n) s[n]=(f32x4){0.f,0.f,0.f,0.f};
        #pragma unroll
        for (int kk=0;kk<2;++kk){
            const int sa = ((kk*64 + lg*16) ^ ((lr&7)<<4));
            #pragma unroll
            for (int n=0;n<4;++n){
                bf16x8 kb = *(const bf16x8*)((const char*)Ks + (n*16+lr)*128 + sa);
                s[n] = __builtin_amdgcn_mfma_f32_16x16x32_bf16(kk? qa1:qa0, kb, s[n], 0,0,0);
            }
        }
        #pragma unroll
        for (int n=0;n<4;++n){
            int col = kt*64 + n*16 + lr;
            bool bad = col >= NTOK;
            #pragma unroll
            for (int e=0;e<4;++e) s[n][e] = bad ? -1e30f : s[n][e]*0.125f;
        }
        #pragma unroll
        for (int e=0;e<4;++e){
            float rm = fmaxf(fmaxf(s[0][e],s[1][e]), fmaxf(s[2][e],s[3][e]));
            rm = fmaxf(rm, __shfl_xor(rm,1));
            rm = fmaxf(rm, __shfl_xor(rm,2));
            rm = fmaxf(rm, __shfl_xor(rm,4));
            rm = fmaxf(rm, __shfl_xor(rm,8));
            float mn = fmaxf(mo[e], rm);
            float al = __expf(mo[e]-mn);
            float rs = 0.f;
            #pragma unroll
            for (int n=0;n<4;++n){ float p=__expf(s[n][e]-mn); s[n][e]=p; rs+=p; }
            rs += __shfl_xor(rs,1); rs += __shfl_xor(rs,2);
            rs += __shfl_xor(rs,4); rs += __shfl_xor(rs,8);
            lo[e] = lo[e]*al + rs; mo[e]=mn;
            #pragma unroll
            for (int n=0;n<4;++n) oacc[n][e] *= al;
        }
        #pragma unroll
        for (int n=0;n<4;++n)
            #pragma unroll
            for (int e=0;e<4;++e)
                Ps[(w*16+lg*4+e)*72 + n*16+lr] = (__bf16)s[n][e];
        // Ps is wave-private (rows w*16..): in-wave ds_write->ds_read ordered by compiler mem-deps
        #pragma unroll
        for (int kk=0;kk<2;++kk){
            bf16x8 pa = *(const bf16x8*)&Ps[(w*16+lr)*72 + kk*32 + lg*8];
            #pragma unroll
            for (int n=0;n<4;++n){
                bf16x8 vf = *(const bf16x8*)&VT[(n*16+lr)*72 + kk*32 + lg*8];
                oacc[n] = __builtin_amdgcn_mfma_f32_16x16x32_bf16(pa, vf, oacc[n], 0,0,0);
            }
        }
    }
    #pragma unroll
    for (int e=0;e<4;++e){
        int q = qt*64 + w*16 + lg*4 + e;
        if (q < NTOK){
            float inv = 1.f/lo[e];
            __bf16* op = O + ((long)b*NTOK + q)*TD + h*64;
            #pragma unroll
            for (int n=0;n<4;++n)
                op[n*16+lr] = (__bf16)(oacc[n][e]*inv);
        }
    }
}

// ---------------- LayerNorm row of 384 (fp32 in, bf16 out) ----------------
__global__ __launch_bounds__(128) void ln_kernel(const float* __restrict__ Xp, __bf16* __restrict__ Y,
    const float* __restrict__ W, const float* __restrict__ Bp)
{
    long r = blockIdx.x;
    int t = threadIdx.x;
    const float* x = Xp + r*TD;
    float v0 = x[t], v1 = x[t+128], v2 = x[t+256];
    float s = v0+v1+v2;
    float q = v0*v0+v1*v1+v2*v2;
    #pragma unroll
    for (int w=1; w<64; w<<=1){ s += __shfl_xor(s,w); q += __shfl_xor(q,w); }
    __shared__ float sm[2][2];
    if ((t&63)==0){ sm[t>>6][0]=s; sm[t>>6][1]=q; }
    __syncthreads();
    float S = sm[0][0]+sm[1][0];
    float Q = sm[0][1]+sm[1][1];
    float mean = S*(1.f/384.f);
    float var  = Q*(1.f/384.f) - mean*mean;
    float rstd = rsqrtf(var + 1e-6f);
    __bf16* y = Y + r*TD;
    y[t]     = (__bf16)((v0-mean)*rstd*W[t]     + Bp[t]);
    y[t+128] = (__bf16)((v1-mean)*rstd*W[t+128] + Bp[t+128]);
    y[t+256] = (__bf16)((v2-mean)*rstd*W[t+256] + Bp[t+256]);
}

// ---------------- weight fp32 -> bf16 ----------------
__global__ void wconv_kernel(const float* __restrict__ s, __bf16* __restrict__ d, int n4){
    int i = blockIdx.x*256 + threadIdx.x;
    if (i < n4){
        float4 v = ((const float4*)s)[i];
        bf16x4 p; p[0]=(__bf16)v.x; p[1]=(__bf16)v.y; p[2]=(__bf16)v.z; p[3]=(__bf16)v.w;
        ((bf16x4*)d)[i] = p;
    }
}

// ---------------- im2col (bf16 out) ----------------
__global__ void im2col_kernel(const float* __restrict__ in, __bf16* __restrict__ outp)
{
    long idx = (long)blockIdx.x*256 + threadIdx.x;
    if (idx >= (long)7680*1792) return;
    int k = (int)(idx % 1792);
    long m = idx / 1792;
    int pw = (int)(m % 40);
    long t2 = m / 40;
    int ph = (int)(t2 % 12);
    int b  = (int)(t2 / 12);
    int kw = k & 15, kh = (k >> 4) & 15, c = k >> 8;
    outp[idx] = (__bf16)in[(((long)(b*7 + c)*192) + ph*16 + kh)*640 + pw*16 + kw];
}

// ---------------- assemble x = [cls; conv_out] + pos (fp32) ----------------
__global__ void assemble_kernel(const float* __restrict__ CO, const float* __restrict__ cls,
    const float* __restrict__ pos, float* __restrict__ X)
{
    long idx = (long)blockIdx.x*256 + threadIdx.x;
    if (idx >= (long)NROWS*TD) return;
    int d = (int)(idx % TD);
    long r = idx / TD;
    int tok = (int)(r % NTOK);
    int b   = (int)(r / NTOK);
    float v = (tok == 0) ? cls[d] : CO[((long)b*480 + tok-1)*TD + d];
    X[idx] = v + pos[tok*TD + d];
}

// ---------------- pose maps ----------------
__global__ __launch_bounds__(256) void pose_maps_kernel(const float* __restrict__ PA,
    float* __restrict__ attn_map, float* __restrict__ masked_map)
{
    int i = blockIdx.x;   // 0..39
    int b = blockIdx.y;   // 0..15
    int t = threadIdx.x;
    float accA[12], accM[12];
    #pragma unroll
    for (int j=0;j<12;++j){ accA[j]=0.f; accM[j]=0.f; }
    for (int a = t; a < 480; a += 256) {
        const float* row = PA + ((long)(b*480 + a))*480 + i;
        float v[12];
        float mx = -1e30f;
        #pragma unroll
        for (int j=0;j<12;++j){ v[j] = row[40*j]; mx = fmaxf(mx, v[j]); }
        float sum = 0.f;
        #pragma unroll
        for (int j=0;j<12;++j){ v[j] = expf(v[j]-mx); sum += v[j]; }
        float invs = 1.f/sum;
        #pragma unroll
        for (int j=0;j<12;++j) v[j] *= invs;
        float srt[12];
        #pragma unroll
        for (int j=0;j<12;++j){
            float x = v[j]; int p = j;
            while (p > 0 && srt[p-1] > x){ srt[p]=srt[p-1]; --p; }
            srt[p]=x;
        }
        float med = srt[5];
        #pragma unroll
        for (int j=0;j<12;++j){
            accA[j] += v[j];
            accM[j] += (v[j] > med) ? 0.f : v[j];
        }
    }
    __shared__ float redA[256*12];
    __shared__ float redM[256*12];
    #pragma unroll
    for (int j=0;j<12;++j){ redA[t*12+j]=accA[j]; redM[t*12+j]=accM[j]; }
    __syncthreads();
    for (int sgap=128; sgap>0; sgap>>=1){
        if (t < sgap){
            #pragma unroll
            for (int j=0;j<12;++j){
                redA[t*12+j] += redA[(t+sgap)*12+j];
                redM[t*12+j] += redM[(t+sgap)*12+j];
            }
        }
        __syncthreads();
    }
    if (t < 12){
        attn_map  [(b*12 + t)*40 + i] = redA[t] * (1.f/480.f);
        masked_map[(b*12 + t)*40 + i] = redM[t] * (1.f/480.f) * (1.f/24.f);
    }
}

// ---------------- column-sum of pose V (bf16 in), 4-way row-split ----------------
__global__ __launch_bounds__(384) void colsum4_kernel(const __bf16* __restrict__ QKV2, float* __restrict__ CS4)
{
    int b = blockIdx.x, j = blockIdx.y, c = threadIdx.x;
    const __bf16* p = QKV2 + (long)b*480*1152 + 768 + c;
    float s = 0.f;
    for (int a = j*120; a < j*120+120; ++a) s += (float)p[(long)a*1152];
    CS4[((long)b*4 + j)*384 + c] = s;
}

// ---------------- final pose output: LN(40*colsum @ pose_w^T + pose_b) ----------------
__global__ __launch_bounds__(384) void pose_final_kernel(const float* __restrict__ CS4,
    const float* __restrict__ PW, const float* __restrict__ PB,
    const float* __restrict__ NW, const float* __restrict__ NBb, float* __restrict__ out)
{
    int b = blockIdx.x, c = threadIdx.x;
    const float* s0 = CS4 + (long)b*1536;
    __shared__ float sv[384];
    sv[c] = s0[c] + s0[384+c] + s0[768+c] + s0[1152+c];
    __syncthreads();
    const float* wr = PW + (long)c*384;
    float acc = 0.f;
    for (int k = 0; k < 384; ++k) acc += sv[k]*wr[k];
    acc = 40.f*acc + PB[c];
    float s = acc, q = acc*acc;
    #pragma unroll
    for (int w=1; w<64; w<<=1){ s += __shfl_xor(s,w); q += __shfl_xor(q,w); }
    __shared__ float sm[6][2];
    if ((c & 63) == 0){ sm[c>>6][0]=s; sm[c>>6][1]=q; }
    __syncthreads();
    float S=0.f, Q=0.f;
    for (int i=0;i<6;++i){ S+=sm[i][0]; Q+=sm[i][1]; }
    float mean = S*(1.f/384.f);
    float var  = Q*(1.f/384.f) - mean*mean;
    float rstd = rsqrtf(var + 1e-6f);
    out[b*384 + c] = (acc-mean)*rstd*NW[c] + NBb[c];
}

extern "C" void kernel_launch(void* const* d_in, const int* in_sizes, int n_in,
                              void* d_out, int out_size, void* d_ws, size_t ws_size,
                              hipStream_t stream)
{
    const float* input  = (const float*)d_in[0];
    const float* conv_w = (const float*)d_in[1];
    const float* conv_b = (const float*)d_in[2];
    const float* cls    = (const float*)d_in[3];
    const float* pos    = (const float*)d_in[4];
    const float* ln1w   = (const float*)d_in[5];
    const float* ln1b   = (const float*)d_in[6];
    const float* qkvw   = (const float*)d_in[7];
    const float* qkvb   = (const float*)d_in[8];
    const float* projw  = (const float*)d_in[9];
    const float* projb  = (const float*)d_in[10];
    const float* ln2w   = (const float*)d_in[11];
    const float* ln2b   = (const float*)d_in[12];
    const float* fc1w   = (const float*)d_in[13];
    const float* fc1b   = (const float*)d_in[14];
    const float* fc2w   = (const float*)d_in[15];
    const float* fc2b   = (const float*)d_in[16];
    const float* normw  = (const float*)d_in[17];
    const float* normb  = (const float*)d_in[18];
    const float* toqkvw = (const float*)d_in[19];
    const float* posew  = (const float*)d_in[20];
    const float* poseb  = (const float*)d_in[21];
    float* out = (float*)d_out;
    float* ws  = (float*)d_ws;

    // ---- workspace layout (float offsets) ----
    __bf16* WB   = (__bf16*)ws;                                  // 22,364,160 bf16 = 11,182,080 f
    float*  X    = ws + 11182080;                                // 7696*384 fp32
    __bf16* Hbf  = (__bf16*)(ws + 11182080 + 2955264);           // 7744*384 bf16
    __bf16* QKVb = (__bf16*)(ws + 11182080 + 2955264 + 1486848); // 7744*1536 bf16
    __bf16* Obuf = (__bf16*)(ws + 11182080 + 2955264 + 1486848 + 5947392); // 7744*384 bf16
    float*  PAb  = ws + 23058432;                                // 16*480*480 fp32 (also conv tmp)
    float*  CS4  = PAb + 3686400;                                // 16*4*384 fp32
    __bf16* IM2C = QKVb;                                         // alias (pre-layer only)

    __bf16* Wconv = WB;
    __bf16* Wqkv  = WB + 688128;
    __bf16* Wproj = WB + 5996544;
    __bf16* Wfc1  = WB + 7766016;
    __bf16* Wfc2  = WB + 14843904;
    __bf16* Wtoq  = WB + 21921792;

    // ---- weights -> bf16 ----
    wconv_kernel<<<dim3((172032+255)/256), 256, 0, stream>>>(conv_w, Wconv, 172032);
    wconv_kernel<<<dim3((1327104+255)/256), 256, 0, stream>>>(qkvw,  Wqkv, 1327104);
    wconv_kernel<<<dim3((442368+255)/256), 256, 0, stream>>>(projw, Wproj, 442368);
    wconv_kernel<<<dim3((1769472+255)/256), 256, 0, stream>>>(fc1w,  Wfc1, 1769472);
    wconv_kernel<<<dim3((1769472+255)/256), 256, 0, stream>>>(fc2w,  Wfc2, 1769472);
    wconv_kernel<<<dim3((110592+255)/256), 256, 0, stream>>>(toqkvw, Wtoq, 110592);

    // ---- patch embed ----
    {
        long total = (long)7680*1792;
        im2col_kernel<<<dim3((unsigned)((total+255)/256)), 256, 0, stream>>>(input, IM2C);
    }
    mgemm<<<dim3(3, 120, 1), 256, 0, stream>>>(IM2C, 1792, 0, Wconv, 1792, 0,
        PAb, 384, 0, conv_b, nullptr, 0, 7680, 384, 1792, 1.f, 0, 0);
    assemble_kernel<<<dim3((NROWS*TD+255)/256), 256, 0, stream>>>(PAb, cls, pos, X);

    // ---- transformer layers ----
    for (int i = 0; i < 12; ++i) {
        ln_kernel<<<dim3(NROWS), 128, 0, stream>>>(X, Hbf, ln1w + i*384, ln1b + i*384);
        mgemm<<<dim3(9, 121, 1), 256, 0, stream>>>(Hbf, 384, 0, Wqkv + (long)i*1152*384, 384, 0,
            QKVb, 1152, 0, qkvb + i*1152, nullptr, 0, NROWS, 1152, 384, 1.f, 0, 1);
        attn2<<<dim3(8, NHEAD, NB), 256, 0, stream>>>(QKVb, Obuf);
        mgemm<<<dim3(3, 121, 1), 256, 0, stream>>>(Obuf, 384, 0, Wproj + (long)i*384*384, 384, 0,
            X, 384, 0, projb + i*384, X, 0, NROWS, 384, 384, 1.f, 0, 0);
        ln_kernel<<<dim3(NROWS), 128, 0, stream>>>(X, Hbf, ln2w + i*384, ln2b + i*384);
        mgemm<<<dim3(12, 121, 1), 256, 0, stream>>>(Hbf, 384, 0, Wfc1 + (long)i*1536*384, 384, 0,
            QKVb, 1536, 0, fc1b + i*1536, nullptr, 0, NROWS, 1536, 384, 1.f, 1, 1);
        mgemm<<<dim3(3, 121, 1), 256, 0, stream>>>(QKVb, 1536, 0, Wfc2 + (long)i*384*1536, 1536, 0,
            X, 384, 0, fc2b + i*384, X, 0, NROWS, 384, 1536, 1.f, 0, 0);
    }
    ln_kernel<<<dim3(NROWS), 128, 0, stream>>>(X, Hbf, normw, normb);

    // ---- pose head ----
    mgemm<<<dim3(9, 8, 16), 256, 0, stream>>>(Hbf + 384, 384, (long)481*384,
        Wtoq, 384, 0, QKVb, 1152, (long)480*1152, nullptr, nullptr, 0, 480, 1152, 384, 1.f, 0, 1);
    mgemm<<<dim3(4, 8, 16), 256, 0, stream>>>(QKVb, 1152, (long)480*1152,
        QKVb + 384, 1152, (long)480*1152, PAb, 480, (long)480*480, nullptr, nullptr, 0,
        480, 480, 384, 0.05103f*0.01f, 0, 0);
    pose_maps_kernel<<<dim3(40, 16), 256, 0, stream>>>(PAb, out + 6144, out + 13824);
    colsum4_kernel<<<dim3(16, 4), 384, 0, stream>>>(QKVb, CS4);
    pose_final_kernel<<<dim3(16), 384, 0, stream>>>(CS4, posew, poseb, normw, normb, out);
}

// Round 4
// 2113.550 us; speedup vs baseline: 3.4111x; 1.0538x over previous
//
#include <hip/hip_runtime.h>
#include <hip/hip_bf16.h>

#define TD 384
#define NHEAD 6
#define NFF 1536
#define NB 16
#define NTOK 481
#define NROWS (NB*NTOK)   // 7696
#define MPAD 7744         // 121*64

typedef __attribute__((ext_vector_type(8))) __bf16 bf16x8;
typedef __attribute__((ext_vector_type(4))) __bf16 bf16x4;
typedef __attribute__((ext_vector_type(4))) float f32x4;

static __device__ __forceinline__ float gelu_f(float v){
    return 0.5f*v*(1.0f + erff(v*0.70710678118654752f));
}

static __device__ __forceinline__ void gload16(const void* g, void* l){
    __builtin_amdgcn_global_load_lds((const __attribute__((address_space(1))) void*)g,
                                     (__attribute__((address_space(3))) void*)l, 16, 0, 0);
}

// stage ROWS x 64 bf16 tile (row-major, 128B rows) into linear LDS via global_load_lds,
// with XOR-swizzled SOURCE address so that a swizzled ds_read returns linear data (T2, rule 21).
template<int ROWS>
static __device__ __forceinline__ void stageT(const __bf16* g, int ldel, __bf16* lds, int w, int lane){
    #pragma unroll
    for (int j = 0; j < ROWS/32; ++j){
        int i = w*(ROWS/32) + j;
        int ol = i*1024 + lane*16;
        int row = ol >> 7, colb = ol & 127;
        int sc = colb ^ ((row & 7) << 4);
        gload16((const char*)g + (long)row*ldel*2 + sc, (char*)lds + i*1024);
    }
}

// ---------------- bf16 MFMA GEMM: C = scale*(A @ B^T) + bias [+gelu] [+R fp32] ----------------
// A: (M,K) bf16 row-major lda (rows padded); B: (N,K) bf16 ldb; C fp32 or bf16 (obf).
// K % 64 == 0. 256 thr = 4 waves (2x2), tile 64x128. Counted-vmcnt 2-phase + XCD swizzle.
__global__ __launch_bounds__(256) void mgemm(
    const __bf16* __restrict__ A, int lda, long sA,
    const __bf16* __restrict__ Bm, int ldb, long sB,
    void* __restrict__ Cp, int ldc, long sC,
    const float* __restrict__ bias,
    const float* __restrict__ Rp, long sR,
    int M, int N, int K, float scale, int act, int obf)
{
    __shared__ __align__(16) __bf16 As[2][64*64];
    __shared__ __align__(16) __bf16 Bs[2][128*64];
    const int bz = blockIdx.z;
    A  += (long)bz*sA; Bm += (long)bz*sB;

    // bijective XCD-chunked swizzle (T1, m204): block bid runs on XCD bid%8;
    // give each XCD a contiguous chunk of the (row-major, x-fastest) tile grid.
    const int nwg = gridDim.x*gridDim.y;
    const int id  = blockIdx.y*gridDim.x + blockIdx.x;
    const int q8  = nwg >> 3, r8 = nwg & 7;
    const int xcd = id & 7, sub = id >> 3;
    const int nid = (xcd < r8 ? xcd*(q8+1) : r8*(q8+1) + (xcd-r8)*q8) + sub;
    const int m0 = (nid / gridDim.x) * 64, n0 = (nid % gridDim.x) * 128;

    const int tid = threadIdx.x;
    const int w = tid >> 6, lane = tid & 63;
    const int wr = w >> 1, wc = w & 1;
    const int lr = lane & 15, lg = lane >> 4;

    f32x4 acc[2][4];
    #pragma unroll
    for (int m=0;m<2;++m)
        #pragma unroll
        for (int n=0;n<4;++n)
            acc[m][n] = (f32x4){0.f,0.f,0.f,0.f};

    const __bf16* Ag = A + (long)m0*lda;
    const __bf16* Bg = Bm + (long)n0*ldb;
    const int NT = K >> 6;

    stageT<64>(Ag, lda, As[0], w, lane);      // 2 loads/thread
    stageT<128>(Bg, ldb, Bs[0], w, lane);     // 4 loads/thread
    int cur = 0;
    for (int t = 0; t < NT; ++t){
        if (t+1 < NT){
            stageT<64>(Ag + (t+1)*64, lda, As[cur^1], w, lane);
            stageT<128>(Bg + (t+1)*64, ldb, Bs[cur^1], w, lane);
            // wait for tile t's 6 loads (oldest); leave tile t+1's 6 in flight (T4)
            asm volatile("s_waitcnt vmcnt(6)" ::: "memory");
        } else {
            asm volatile("s_waitcnt vmcnt(0)" ::: "memory");
        }
        __builtin_amdgcn_sched_barrier(0);
        __builtin_amdgcn_s_barrier();          // tile t fully in LDS for all waves
        #pragma unroll
        for (int kk=0;kk<2;++kk){
            const int sa = ((kk*64 + lg*16) ^ ((lr&7)<<4));
            bf16x8 af[2], bfr[4];
            #pragma unroll
            for (int m=0;m<2;++m)
                af[m] = *(const bf16x8*)((const char*)&As[cur][0] + (wr*32 + m*16 + lr)*128 + sa);
            #pragma unroll
            for (int n=0;n<4;++n)
                bfr[n] = *(const bf16x8*)((const char*)&Bs[cur][0] + (wc*64 + n*16 + lr)*128 + sa);
            #pragma unroll
            for (int m=0;m<2;++m)
                #pragma unroll
                for (int n=0;n<4;++n)
                    acc[m][n] = __builtin_amdgcn_mfma_f32_16x16x32_bf16(af[m], bfr[n], acc[m][n], 0, 0, 0);
        }
        __builtin_amdgcn_s_barrier();          // all waves done reading buf[cur] before next stage overwrites it
        cur ^= 1;
    }

    #pragma unroll
    for (int m=0;m<2;++m){
        #pragma unroll
        for (int n=0;n<4;++n){
            int col = n0 + wc*64 + n*16 + lr;
            if (col >= N) continue;
            #pragma unroll
            for (int e=0;e<4;++e){
                int row = m0 + wr*32 + m*16 + lg*4 + e;
                if (row >= M) continue;
                float v = acc[m][n][e]*scale;
                if (bias) v += bias[col];
                if (act) v = gelu_f(v);
                if (Rp) v += Rp[(long)bz*sR + (long)row*ldc + col];
                if (obf) ((__bf16*)Cp)[(long)bz*sC + (long)row*ldc + col] = (__bf16)v;
                else     ((float*)Cp)[(long)bz*sC + (long)row*ldc + col] = v;
            }
        }
    }
}

// ---------------- MFMA flash attention: block = (q-tile 64, head, batch), 4 waves ----------------
__global__ __launch_bounds__(256) void attn2(const __bf16* __restrict__ QKV, __bf16* __restrict__ O)
{
    __shared__ __align__(16) __bf16 Ks[64*64];
    __shared__ __align__(16) __bf16 VT[64*72];
    __shared__ __align__(16) __bf16 Ps[64*72];
    const int qt=blockIdx.x, h=blockIdx.y, b=blockIdx.z;
    const int tid=threadIdx.x, w=tid>>6, lane=tid&63;
    const int lr=lane&15, lg=lane>>4;
    const __bf16* base = QKV + (long)b*NTOK*1152;
    const long qrow = qt*64 + w*16 + lr;
    const bf16x8 qa0 = *(const bf16x8*)(base + qrow*1152 + h*64 + lg*8);
    const bf16x8 qa1 = *(const bf16x8*)(base + qrow*1152 + h*64 + 32 + lg*8);

    f32x4 oacc[4];
    float mo[4], lo[4];
    #pragma unroll
    for (int e=0;e<4;++e){ mo[e]=-1e30f; lo[e]=0.f; }
    #pragma unroll
    for (int n=0;n<4;++n) oacc[n]=(f32x4){0.f,0.f,0.f,0.f};

    for (int kt=0; kt<8; ++kt){
        __syncthreads();   // previous iteration's LDS readers done
        #pragma unroll
        for (int j=0;j<2;++j){
            int i = w*2+j;
            int ol = i*1024 + lane*16;
            int row = ol>>7, colb = ol&127;
            int sc = colb ^ ((row&7)<<4);
            gload16((const char*)base + ((long)(kt*64+row)*1152 + 384 + h*64)*2 + sc,
                    (char*)Ks + i*1024);
        }
        #pragma unroll
        for (int rep=0;rep<2;++rep){
            int c = tid + rep*256;
            int kv = c & 63, d8 = c >> 6;
            bf16x8 vv = *(const bf16x8*)(base + (long)(kt*64+kv)*1152 + 768 + h*64 + d8*8);
            #pragma unroll
            for (int jj=0;jj<8;++jj) VT[(d8*8+jj)*72 + kv] = vv[jj];
        }
        __syncthreads();   // staging visible

        f32x4 s[4];
        #pragma unroll
        for (int n=0;n<4;++n) s[n]=(f32x4){0.f,0.f,0.f,0.f};
        #pragma unroll
        for (int kk=0;kk<2;++kk){
            const int sa = ((kk*64 + lg*16) ^ ((lr&7)<<4));
            #pragma unroll
            for (int n=0;n<4;++n){
                bf16x8 kb = *(const bf16x8*)((const char*)Ks + (n*16+lr)*128 + sa);
                s[n] = __builtin_amdgcn_mfma_f32_16x16x32_bf16(kk? qa1:qa0, kb, s[n], 0,0,0);
            }
        }
        #pragma unroll
        for (int n=0;n<4;++n){
            int col = kt*64 + n*16 + lr;
            bool bad = col >= NTOK;
            #pragma unroll
            for (int e=0;e<4;++e) s[n][e] = bad ? -1e30f : s[n][e]*0.125f;
        }
        #pragma unroll
        for (int e=0;e<4;++e){
            float rm = fmaxf(fmaxf(s[0][e],s[1][e]), fmaxf(s[2][e],s[3][e]));
            rm = fmaxf(rm, __shfl_xor(rm,1));
            rm = fmaxf(rm, __shfl_xor(rm,2));
            rm = fmaxf(rm, __shfl_xor(rm,4));
            rm = fmaxf(rm, __shfl_xor(rm,8));
            float mn = fmaxf(mo[e], rm);
            float al = __expf(mo[e]-mn);
            float rs = 0.f;
            #pragma unroll
            for (int n=0;n<4;++n){ float p=__expf(s[n][e]-mn); s[n][e]=p; rs+=p; }
            rs += __shfl_xor(rs,1); rs += __shfl_xor(rs,2);
            rs += __shfl_xor(rs,4); rs += __shfl_xor(rs,8);
            lo[e] = lo[e]*al + rs; mo[e]=mn;
            #pragma unroll
            for (int n=0;n<4;++n) oacc[n][e] *= al;
        }
        #pragma unroll
        for (int n=0;n<4;++n)
            #pragma unroll
            for (int e=0;e<4;++e)
                Ps[(w*16+lg*4+e)*72 + n*16+lr] = (__bf16)s[n][e];
        #pragma unroll
        for (int kk=0;kk<2;++kk){
            bf16x8 pa = *(const bf16x8*)&Ps[(w*16+lr)*72 + kk*32 + lg*8];
            #pragma unroll
            for (int n=0;n<4;++n){
                bf16x8 vf = *(const bf16x8*)&VT[(n*16+lr)*72 + kk*32 + lg*8];
                oacc[n] = __builtin_amdgcn_mfma_f32_16x16x32_bf16(pa, vf, oacc[n], 0,0,0);
            }
        }
    }
    #pragma unroll
    for (int e=0;e<4;++e){
        int q = qt*64 + w*16 + lg*4 + e;
        if (q < NTOK){
            float inv = 1.f/lo[e];
            __bf16* op = O + ((long)b*NTOK + q)*TD + h*64;
            #pragma unroll
            for (int n=0;n<4;++n)
                op[n*16+lr] = (__bf16)(oacc[n][e]*inv);
        }
    }
}

// ---------------- LayerNorm row of 384 (fp32 in, bf16 out) ----------------
__global__ __launch_bounds__(128) void ln_kernel(const float* __restrict__ Xp, __bf16* __restrict__ Y,
    const float* __restrict__ W, const float* __restrict__ Bp)
{
    long r = blockIdx.x;
    int t = threadIdx.x;
    const float* x = Xp + r*TD;
    float v0 = x[t], v1 = x[t+128], v2 = x[t+256];
    float s = v0+v1+v2;
    float q = v0*v0+v1*v1+v2*v2;
    #pragma unroll
    for (int w=1; w<64; w<<=1){ s += __shfl_xor(s,w); q += __shfl_xor(q,w); }
    __shared__ float sm[2][2];
    if ((t&63)==0){ sm[t>>6][0]=s; sm[t>>6][1]=q; }
    __syncthreads();
    float S = sm[0][0]+sm[1][0];
    float Q = sm[0][1]+sm[1][1];
    float mean = S*(1.f/384.f);
    float var  = Q*(1.f/384.f) - mean*mean;
    float rstd = rsqrtf(var + 1e-6f);
    __bf16* y = Y + r*TD;
    y[t]     = (__bf16)((v0-mean)*rstd*W[t]     + Bp[t]);
    y[t+128] = (__bf16)((v1-mean)*rstd*W[t+128] + Bp[t+128]);
    y[t+256] = (__bf16)((v2-mean)*rstd*W[t+256] + Bp[t+256]);
}

// ---------------- weight fp32 -> bf16 ----------------
__global__ void wconv_kernel(const float* __restrict__ s, __bf16* __restrict__ d, int n4){
    int i = blockIdx.x*256 + threadIdx.x;
    if (i < n4){
        float4 v = ((const float4*)s)[i];
        bf16x4 p; p[0]=(__bf16)v.x; p[1]=(__bf16)v.y; p[2]=(__bf16)v.z; p[3]=(__bf16)v.w;
        ((bf16x4*)d)[i] = p;
    }
}

// ---------------- im2col (bf16 out) ----------------
__global__ void im2col_kernel(const float* __restrict__ in, __bf16* __restrict__ outp)
{
    long idx = (long)blockIdx.x*256 + threadIdx.x;
    if (idx >= (long)7680*1792) return;
    int k = (int)(idx % 1792);
    long m = idx / 1792;
    int pw = (int)(m % 40);
    long t2 = m / 40;
    int ph = (int)(t2 % 12);
    int b  = (int)(t2 / 12);
    int kw = k & 15, kh = (k >> 4) & 15, c = k >> 8;
    outp[idx] = (__bf16)in[(((long)(b*7 + c)*192) + ph*16 + kh)*640 + pw*16 + kw];
}

// ---------------- assemble x = [cls; conv_out] + pos (fp32) ----------------
__global__ void assemble_kernel(const float* __restrict__ CO, const float* __restrict__ cls,
    const float* __restrict__ pos, float* __restrict__ X)
{
    long idx = (long)blockIdx.x*256 + threadIdx.x;
    if (idx >= (long)NROWS*TD) return;
    int d = (int)(idx % TD);
    long r = idx / TD;
    int tok = (int)(r % NTOK);
    int b   = (int)(r / NTOK);
    float v = (tok == 0) ? cls[d] : CO[((long)b*480 + tok-1)*TD + d];
    X[idx] = v + pos[tok*TD + d];
}

// ---------------- pose maps ----------------
__global__ __launch_bounds__(256) void pose_maps_kernel(const float* __restrict__ PA,
    float* __restrict__ attn_map, float* __restrict__ masked_map)
{
    int i = blockIdx.x;   // 0..39
    int b = blockIdx.y;   // 0..15
    int t = threadIdx.x;
    float accA[12], accM[12];
    #pragma unroll
    for (int j=0;j<12;++j){ accA[j]=0.f; accM[j]=0.f; }
    for (int a = t; a < 480; a += 256) {
        const float* row = PA + ((long)(b*480 + a))*480 + i;
        float v[12];
        float mx = -1e30f;
        #pragma unroll
        for (int j=0;j<12;++j){ v[j] = row[40*j]; mx = fmaxf(mx, v[j]); }
        float sum = 0.f;
        #pragma unroll
        for (int j=0;j<12;++j){ v[j] = expf(v[j]-mx); sum += v[j]; }
        float invs = 1.f/sum;
        #pragma unroll
        for (int j=0;j<12;++j) v[j] *= invs;
        float srt[12];
        #pragma unroll
        for (int j=0;j<12;++j){
            float x = v[j]; int p = j;
            while (p > 0 && srt[p-1] > x){ srt[p]=srt[p-1]; --p; }
            srt[p]=x;
        }
        float med = srt[5];
        #pragma unroll
        for (int j=0;j<12;++j){
            accA[j] += v[j];
            accM[j] += (v[j] > med) ? 0.f : v[j];
        }
    }
    __shared__ float redA[256*12];
    __shared__ float redM[256*12];
    #pragma unroll
    for (int j=0;j<12;++j){ redA[t*12+j]=accA[j]; redM[t*12+j]=accM[j]; }
    __syncthreads();
    for (int sgap=128; sgap>0; sgap>>=1){
        if (t < sgap){
            #pragma unroll
            for (int j=0;j<12;++j){
                redA[t*12+j] += redA[(t+sgap)*12+j];
                redM[t*12+j] += redM[(t+sgap)*12+j];
            }
        }
        __syncthreads();
    }
    if (t < 12){
        attn_map  [(b*12 + t)*40 + i] = redA[t] * (1.f/480.f);
        masked_map[(b*12 + t)*40 + i] = redM[t] * (1.f/480.f) * (1.f/24.f);
    }
}

// ---------------- column-sum of pose V (bf16 in), 4-way row-split ----------------
__global__ __launch_bounds__(384) void colsum4_kernel(const __bf16* __restrict__ QKV2, float* __restrict__ CS4)
{
    int b = blockIdx.x, j = blockIdx.y, c = threadIdx.x;
    const __bf16* p = QKV2 + (long)b*480*1152 + 768 + c;
    float s = 0.f;
    for (int a = j*120; a < j*120+120; ++a) s += (float)p[(long)a*1152];
    CS4[((long)b*4 + j)*384 + c] = s;
}

// ---------------- final pose output: LN(40*colsum @ pose_w^T + pose_b) ----------------
__global__ __launch_bounds__(384) void pose_final_kernel(const float* __restrict__ CS4,
    const float* __restrict__ PW, const float* __restrict__ PB,
    const float* __restrict__ NW, const float* __restrict__ NBb, float* __restrict__ out)
{
    int b = blockIdx.x, c = threadIdx.x;
    const float* s0 = CS4 + (long)b*1536;
    __shared__ float sv[384];
    sv[c] = s0[c] + s0[384+c] + s0[768+c] + s0[1152+c];
    __syncthreads();
    const float* wr = PW + (long)c*384;
    float acc = 0.f;
    for (int k = 0; k < 384; ++k) acc += sv[k]*wr[k];
    acc = 40.f*acc + PB[c];
    float s = acc, q = acc*acc;
    #pragma unroll
    for (int w=1; w<64; w<<=1){ s += __shfl_xor(s,w); q += __shfl_xor(q,w); }
    __shared__ float sm[6][2];
    if ((c & 63) == 0){ sm[c>>6][0]=s; sm[c>>6][1]=q; }
    __syncthreads();
    float S=0.f, Q=0.f;
    for (int i=0;i<6;++i){ S+=sm[i][0]; Q+=sm[i][1]; }
    float mean = S*(1.f/384.f);
    float var  = Q*(1.f/384.f) - mean*mean;
    float rstd = rsqrtf(var + 1e-6f);
    out[b*384 + c] = (acc-mean)*rstd*NW[c] + NBb[c];
}

extern "C" void kernel_launch(void* const* d_in, const int* in_sizes, int n_in,
                              void* d_out, int out_size, void* d_ws, size_t ws_size,
                              hipStream_t stream)
{
    const float* input  = (const float*)d_in[0];
    const float* conv_w = (const float*)d_in[1];
    const float* conv_b = (const float*)d_in[2];
    const float* cls    = (const float*)d_in[3];
    const float* pos    = (const float*)d_in[4];
    const float* ln1w   = (const float*)d_in[5];
    const float* ln1b   = (const float*)d_in[6];
    const float* qkvw   = (const float*)d_in[7];
    const float* qkvb   = (const float*)d_in[8];
    const float* projw  = (const float*)d_in[9];
    const float* projb  = (const float*)d_in[10];
    const float* ln2w   = (const float*)d_in[11];
    const float* ln2b   = (const float*)d_in[12];
    const float* fc1w   = (const float*)d_in[13];
    const float* fc1b   = (const float*)d_in[14];
    const float* fc2w   = (const float*)d_in[15];
    const float* fc2b   = (const float*)d_in[16];
    const float* normw  = (const float*)d_in[17];
    const float* normb  = (const float*)d_in[18];
    const float* toqkvw = (const float*)d_in[19];
    const float* posew  = (const float*)d_in[20];
    const float* poseb  = (const float*)d_in[21];
    float* out = (float*)d_out;
    float* ws  = (float*)d_ws;

    // ---- workspace layout (float offsets) ----
    __bf16* WB   = (__bf16*)ws;
    float*  X    = ws + 11182080;
    __bf16* Hbf  = (__bf16*)(ws + 11182080 + 2955264);
    __bf16* QKVb = (__bf16*)(ws + 11182080 + 2955264 + 1486848);
    __bf16* Obuf = (__bf16*)(ws + 11182080 + 2955264 + 1486848 + 5947392);
    float*  PAb  = ws + 23058432;
    float*  CS4  = PAb + 3686400;
    __bf16* IM2C = QKVb;

    __bf16* Wconv = WB;
    __bf16* Wqkv  = WB + 688128;
    __bf16* Wproj = WB + 5996544;
    __bf16* Wfc1  = WB + 7766016;
    __bf16* Wfc2  = WB + 14843904;
    __bf16* Wtoq  = WB + 21921792;

    // ---- weights -> bf16 ----
    wconv_kernel<<<dim3((172032+255)/256), 256, 0, stream>>>(conv_w, Wconv, 172032);
    wconv_kernel<<<dim3((1327104+255)/256), 256, 0, stream>>>(qkvw,  Wqkv, 1327104);
    wconv_kernel<<<dim3((442368+255)/256), 256, 0, stream>>>(projw, Wproj, 442368);
    wconv_kernel<<<dim3((1769472+255)/256), 256, 0, stream>>>(fc1w,  Wfc1, 1769472);
    wconv_kernel<<<dim3((1769472+255)/256), 256, 0, stream>>>(fc2w,  Wfc2, 1769472);
    wconv_kernel<<<dim3((110592+255)/256), 256, 0, stream>>>(toqkvw, Wtoq, 110592);

    // ---- patch embed ----
    {
        long total = (long)7680*1792;
        im2col_kernel<<<dim3((unsigned)((total+255)/256)), 256, 0, stream>>>(input, IM2C);
    }
    mgemm<<<dim3(3, 120, 1), 256, 0, stream>>>(IM2C, 1792, 0, Wconv, 1792, 0,
        PAb, 384, 0, conv_b, nullptr, 0, 7680, 384, 1792, 1.f, 0, 0);
    assemble_kernel<<<dim3((NROWS*TD+255)/256), 256, 0, stream>>>(PAb, cls, pos, X);

    // ---- transformer layers ----
    for (int i = 0; i < 12; ++i) {
        ln_kernel<<<dim3(NROWS), 128, 0, stream>>>(X, Hbf, ln1w + i*384, ln1b + i*384);
        mgemm<<<dim3(9, 121, 1), 256, 0, stream>>>(Hbf, 384, 0, Wqkv + (long)i*1152*384, 384, 0,
            QKVb, 1152, 0, qkvb + i*1152, nullptr, 0, NROWS, 1152, 384, 1.f, 0, 1);
        attn2<<<dim3(8, NHEAD, NB), 256, 0, stream>>>(QKVb, Obuf);
        mgemm<<<dim3(3, 121, 1), 256, 0, stream>>>(Obuf, 384, 0, Wproj + (long)i*384*384, 384, 0,
            X, 384, 0, projb + i*384, X, 0, NROWS, 384, 384, 1.f, 0, 0);
        ln_kernel<<<dim3(NROWS), 128, 0, stream>>>(X, Hbf, ln2w + i*384, ln2b + i*384);
        mgemm<<<dim3(12, 121, 1), 256, 0, stream>>>(Hbf, 384, 0, Wfc1 + (long)i*1536*384, 384, 0,
            QKVb, 1536, 0, fc1b + i*1536, nullptr, 0, NROWS, 1536, 384, 1.f, 1, 1);
        mgemm<<<dim3(3, 121, 1), 256, 0, stream>>>(QKVb, 1536, 0, Wfc2 + (long)i*384*1536, 1536, 0,
            X, 384, 0, fc2b + i*384, X, 0, NROWS, 384, 1536, 1.f, 0, 0);
    }
    ln_kernel<<<dim3(NROWS), 128, 0, stream>>>(X, Hbf, normw, normb);

    // ---- pose head ----
    mgemm<<<dim3(9, 8, 16), 256, 0, stream>>>(Hbf + 384, 384, (long)481*384,
        Wtoq, 384, 0, QKVb, 1152, (long)480*1152, nullptr, nullptr, 0, 480, 1152, 384, 1.f, 0, 1);
    mgemm<<<dim3(4, 8, 16), 256, 0, stream>>>(QKVb, 1152, (long)480*1152,
        QKVb + 384, 1152, (long)480*1152, PAb, 480, (long)480*480, nullptr, nullptr, 0,
        480, 480, 384, 0.05103f*0.01f, 0, 0);
    pose_maps_kernel<<<dim3(40, 16), 256, 0, stream>>>(PAb, out + 6144, out + 13824);
    colsum4_kernel<<<dim3(16, 4), 384, 0, stream>>>(QKVb, CS4);
    pose_final_kernel<<<dim3(16), 384, 0, stream>>>(CS4, posew, poseb, normw, normb, out);
}